// Round 15
// baseline (21.085 us; speedup 1.0000x reference)
//
#include <hip/hip_runtime.h>
#include <stdint.h>

typedef _Float16 half_t;
typedef _Float16 v4h __attribute__((ext_vector_type(4)));
typedef _Float16 v8h __attribute__((ext_vector_type(8)));
typedef float v4f __attribute__((ext_vector_type(4)));

#define HH 256
#define WW 256
#define HW (HH*WW)
#define TH 32
#define TW 16
#define NRLDS 45          // rows 0..28 = stage A; 29..44 = stage B (16 rows = 1024 units)
#define NPX   (TW+16)     // 32
#define PXS   40          // f16 per px: 32 ch (unit-reordered) + 8 pad; 80B stride
#define RSTEP (NPX*PXS)
#define NTHREADS 1024
#define UA 1856           // 29 rows * 64 units
#define L2E 1.44269504088896340736f

__global__ __launch_bounds__(NTHREADS, 4)
void corr_recon(const float* __restrict__ ft, const float* __restrict__ fr,
                const float* __restrict__ img, float* __restrict__ out)
{
    __shared__ half_t frl[NRLDS * RSTEP];       // 115200 B
    __shared__ float  img_lds[NRLDS * NPX];     // 5760 B

    // XCD-chunked bijective swizzle: 256 blocks = 8 chunks of 32
    const int bid0 = blockIdx.x;
    const int bid  = (bid0 & 7) * 32 + (bid0 >> 3);

    const int b0  = bid >> 7;
    const int rb  = bid & 127;
    const int y0  = (rb >> 4) * TH;    // 8 row-bands of 32
    const int x0t = (rb & 15) * TW;    // 16 col-bands of 16

    const int tid  = threadIdx.x;
    const int lane = tid & 63;
    const int w    = tid >> 6;         // wave 0..15 -> query rows y0+w (B), y0+w+16 (C)
    const int n    = lane & 15;        // MFMA col lane (key px slot)
    const int g    = lane >> 4;        // MFMA k-group

    const float* frb = fr  + (size_t)b0 * 32 * HW;
    const float* ftb = ft  + (size_t)b0 * 32 * HW;
    const float* imb = img + (size_t)b0 * HW;

    // granule q (ch 4q..4q+3) -> f16 offset 8*(q&3)+4*(q>>2): 16B unit at
    // offset 16g = the mfma_f32_16x16x32_f16 k-slice for lane group g.
    auto LD = [&](int i, float4* t4) {
        const int px4 = i & 7;
        const int q   = (i >> 3) & 7;
        const int row = i >> 6;
        const int gy  = y0 - 6 + row;
        const int gx  = x0t - 6 + px4 * 4;
        const int gyc = min(max(gy, 0), HH-1);
        const bool oky = (gy == gyc);
        const float* src = frb + ((size_t)(4*q) * HH + gyc) * WW;
        if (oky && gx >= 0 && gx + 3 < WW) {
            #pragma unroll
            for (int jc = 0; jc < 4; ++jc)
                t4[jc] = *(const float4*)(src + (size_t)jc * HW + gx);
        } else {
            #pragma unroll
            for (int jc = 0; jc < 4; ++jc) {
                const float* s = src + (size_t)jc * HW;
                float e0=0.f, e1=0.f, e2=0.f, e3=0.f;
                if (oky) {
                    e0 = (gx   >= 0 && gx   < WW) ? s[gx]   : 0.f;
                    e1 = (gx+1 >= 0 && gx+1 < WW) ? s[gx+1] : 0.f;
                    e2 = (gx+2 >= 0 && gx+2 < WW) ? s[gx+2] : 0.f;
                    e3 = (gx+3 >= 0 && gx+3 < WW) ? s[gx+3] : 0.f;
                }
                t4[jc].x=e0; t4[jc].y=e1; t4[jc].z=e2; t4[jc].w=e3;
            }
        }
    };
    auto WR = [&](int i, const float4* t4) {
        const int px4 = i & 7;
        const int q   = (i >> 3) & 7;
        const int row = i >> 6;
        const int qo  = 8*(q & 3) + 4*(q >> 2);
        const float t0[4] = {t4[0].x, t4[0].y, t4[0].z, t4[0].w};
        const float t1[4] = {t4[1].x, t4[1].y, t4[1].z, t4[1].w};
        const float t2[4] = {t4[2].x, t4[2].y, t4[2].z, t4[2].w};
        const float t3[4] = {t4[3].x, t4[3].y, t4[3].z, t4[3].w};
        #pragma unroll
        for (int jp = 0; jp < 4; ++jp) {
            const int px = px4 * 4 + jp;
            v4h pk;
            pk[0] = (half_t)t0[jp]; pk[1] = (half_t)t1[jp];
            pk[2] = (half_t)t2[jp]; pk[3] = (half_t)t3[jp];
            *(v4h*)&frl[(row * NPX + px) * PXS + qo] = pk;
        }
    };

    // ---- stage A: rows 0..28 (1856 units), loads first ----
    float4 tA[4], tB[4], tn[4];
    LD(tid, tA);
    const bool has2 = (tid < UA - NTHREADS);       // 832 threads
    if (has2) LD(tid + NTHREADS, tB);

    // img tile rows 0..44 (360 quads; edge quads per-element)
    if (tid < NRLDS * 8) {
        const int px4 = tid & 7;
        const int row = tid >> 3;
        const int gy = y0 - 6 + row;
        const int gx = x0t - 6 + px4*4;
        const int gyc = min(max(gy, 0), HH-1);
        const bool oky = (gy == gyc);
        const float* p = imb + (size_t)gyc * WW;
        float v[4];
        if (oky && gx >= 0 && gx + 3 < WW) {
            float4 t4 = *(const float4*)(p + gx);
            v[0]=t4.x; v[1]=t4.y; v[2]=t4.z; v[3]=t4.w;
        } else {
            #pragma unroll
            for (int e = 0; e < 4; ++e) {
                int x = gx + e;
                v[e] = (oky && x >= 0 && x < WW) ? p[x] : 0.f;
            }
        }
        float4 f4; f4.x=v[0]; f4.y=v[1]; f4.z=v[2]; f4.w=v[3];
        *(float4*)&img_lds[row*NPX + px4*4] = f4;
    }

    // A fragments: query rows y0+w and y0+w+16, pre-scaled by log2e
    const int y = y0 + w;
    v8h a0, a1;
    {
        const float* fa = ftb + (size_t)y * WW + (x0t + n);
        #pragma unroll
        for (int j = 0; j < 4; ++j) {
            a0[j]   = (half_t)(fa[(size_t)(4*g + j)      * HW] * L2E);
            a0[4+j] = (half_t)(fa[(size_t)(16 + 4*g + j) * HW] * L2E);
            a1[j]   = (half_t)(fa[16*WW + (size_t)(4*g + j)      * HW] * L2E);
            a1[4+j] = (half_t)(fa[16*WW + (size_t)(16 + 4*g + j) * HW] * L2E);
        }
    }

    WR(tid, tA);
    if (has2) WR(tid + NTHREADS, tB);

    // ---- stage B loads LAST (in-order vmcnt: nothing after these is consumed
    //      before the barrier, so they stay in flight across it) ----
    LD(tid + UA, tn);                              // rows 29..44, 1 unit/thread

    // per-lane displacement-band biases (log2 domain; exp2(-1e4)==0)
    v4f bias0, bias1;
    #pragma unroll
    for (int r = 0; r < 4; ++r) {
        const int m  = 4*g + r;
        const int d0 = n - m;
        const int d1 = 16 + n - m;
        bias0[r] = (d0 >= 0 && d0 <= 12) ? 0.f : -1e4f;
        bias1[r] = (d1 >= 0 && d1 <= 12) ? 0.f : -1e4f;
    }
    const int dm = n - 4*g;

    auto STEP = [&](const v8h& a, v4f& lp, v4f& ap,
                    const v8h& B0, const v8h& B1, float iw0, float iw1) {
        v4f c0 = __builtin_amdgcn_mfma_f32_16x16x32_f16(a, B0, bias0, 0, 0, 0);
        v4f c1 = __builtin_amdgcn_mfma_f32_16x16x32_f16(a, B1, bias1, 0, 0, 0);
        #pragma unroll
        for (int r = 0; r < 4; ++r) {
            const bool cond = (dm >= r);
            float cs  = cond ? c0[r] : c1[r];
            float iws = cond ? iw0   : iw1;
            float e = __builtin_amdgcn_exp2f(cs);
            lp[r] += e;
            ap[r] += e * iws;
        }
    };

    // single-row half: 13 STEPs over LDS rows rowb..rowb+12, 1-deep prefetch
    auto half = [&](const v8h& a, int rowb, v4f& lp, v4f& ap) {
        const half_t* prd = &frl[(rowb * NPX + n) * PXS + 8*g];
        const float*  ird = &img_lds[rowb * NPX + n];
        v8h C0 = *(const v8h*)(prd);
        v8h C1 = *(const v8h*)(prd + 16*PXS);
        float ci0 = ird[0], ci1 = ird[16];
        prd += RSTEP; ird += NPX;
        v8h N0 = *(const v8h*)(prd);
        v8h N1 = *(const v8h*)(prd + 16*PXS);
        float ni0 = ird[0], ni1 = ird[16];
        STEP(a, lp, ap, C0, C1, ci0, ci1);         // dy = 0
        #pragma unroll 1
        for (int rr = 1; rr < 13; ++rr) {
            C0 = N0; C1 = N1; ci0 = ni0; ci1 = ni1;
            prd += RSTEP; ird += NPX;
            N0 = *(const v8h*)(prd);
            N1 = *(const v8h*)(prd + 16*PXS);
            ni0 = ird[0]; ni1 = ird[16];
            STEP(a, lp, ap, C0, C1, ci0, ci1);     // dy = rr
        }
    };

    v4f lp0 = {0,0,0,0}, ap0 = {0,0,0,0};
    v4f lp1 = {0,0,0,0}, ap1 = {0,0,0,0};

    __syncthreads();                               // rows 0..28 + img visible

    half(a0, w, lp0, ap0);                         // ALL waves: 13 STEPs (rows <= 28)

    WR(tid + UA, tn);                              // vmcnt drain hidden under half0
    __syncthreads();                               // rows 29..44 visible

    half(a1, w + 16, lp1, ap1);                    // ALL waves: 13 STEPs (rows <= 44)

    // ---- reduce over the 16 key-px lanes; write rows y0+w and y0+w+16 ----
    #pragma unroll
    for (int r = 0; r < 4; ++r) {
        float l0 = lp0[r], v0 = ap0[r], l1 = lp1[r], v1 = ap1[r];
        l0 += __shfl_xor(l0, 1);  v0 += __shfl_xor(v0, 1);
        l1 += __shfl_xor(l1, 1);  v1 += __shfl_xor(v1, 1);
        l0 += __shfl_xor(l0, 2);  v0 += __shfl_xor(v0, 2);
        l1 += __shfl_xor(l1, 2);  v1 += __shfl_xor(v1, 2);
        l0 += __shfl_xor(l0, 4);  v0 += __shfl_xor(v0, 4);
        l1 += __shfl_xor(l1, 4);  v1 += __shfl_xor(v1, 4);
        l0 += __shfl_xor(l0, 8);  v0 += __shfl_xor(v0, 8);
        l1 += __shfl_xor(l1, 8);  v1 += __shfl_xor(v1, 8);
        lp0[r] = l0; ap0[r] = v0; lp1[r] = l1; ap1[r] = v1;
    }
    if (n < 4) {
        const float l0 = n==0 ? lp0[0] : n==1 ? lp0[1] : n==2 ? lp0[2] : lp0[3];
        const float v0 = n==0 ? ap0[0] : n==1 ? ap0[1] : n==2 ? ap0[2] : ap0[3];
        const float l1 = n==0 ? lp1[0] : n==1 ? lp1[1] : n==2 ? lp1[2] : lp1[3];
        const float v1 = n==0 ? ap1[0] : n==1 ? ap1[1] : n==2 ? ap1[2] : ap1[3];
        float* op = out + (size_t)b0 * HW + (size_t)y * WW + x0t + 4*g + n;
        op[0]       = v0 / l0;
        op[16 * WW] = v1 / l1;
    }
}

extern "C" void kernel_launch(void* const* d_in, const int* in_sizes, int n_in,
                              void* d_out, int out_size, void* d_ws, size_t ws_size,
                              hipStream_t stream)
{
    const float* ft  = (const float*)d_in[0];  // feats_t  (2,32,256,256) f32
    const float* fr  = (const float*)d_in[1];  // feats_r  (2,32,256,256) f32
    const float* img = (const float*)d_in[2];  // img_r    (2,1,256,256)  f32
    float* out = (float*)d_out;                // (2,1,256,256) f32
    (void)in_sizes; (void)n_in; (void)out_size; (void)d_ws; (void)ws_size;
    corr_recon<<<256, NTHREADS, 0, stream>>>(ft, fr, img, out);
}

// Round 16
// 19.558 us; speedup vs baseline: 1.0781x; 1.0781x over previous
//
#include <hip/hip_runtime.h>
#include <stdint.h>

typedef _Float16 half_t;
typedef _Float16 v4h __attribute__((ext_vector_type(4)));
typedef _Float16 v8h __attribute__((ext_vector_type(8)));
typedef float v4f __attribute__((ext_vector_type(4)));

#define HH 256
#define WW 256
#define HW (HH*WW)
#define TH 32
#define TW 16
#define NROWS (TH+12)     // 44
#define NPX   (TW+16)     // 32
#define PXS   40          // f16 per px: 32 ch (unit-reordered) + 8 pad; 80B stride
#define RSTEP (NPX*PXS)
#define NTHREADS 1024
#define L2E 1.44269504088896340736f

__global__ __launch_bounds__(NTHREADS, 4)
void corr_recon(const float* __restrict__ ft, const float* __restrict__ fr,
                const float* __restrict__ img, float* __restrict__ out)
{
    __shared__ half_t frl[NROWS * RSTEP];       // 112640 B (img no longer in LDS)

    // XCD-chunked bijective swizzle: 256 blocks = 8 chunks of 32
    const int bid0 = blockIdx.x;
    const int bid  = (bid0 & 7) * 32 + (bid0 >> 3);

    const int b0  = bid >> 7;
    const int rb  = bid & 127;
    const int y0  = (rb >> 4) * TH;    // 8 row-bands of 32
    const int x0t = (rb & 15) * TW;    // 16 col-bands of 16

    const int tid  = threadIdx.x;
    const int lane = tid & 63;
    const int w    = tid >> 6;         // wave 0..15 -> query rows y0+2w, y0+2w+1
    const int n    = lane & 15;        // MFMA col lane (key px slot)
    const int g    = lane >> 4;        // MFMA k-group

    const float* frb = fr  + (size_t)b0 * 32 * HW;
    const float* ftb = ft  + (size_t)b0 * 32 * HW;
    const float* imb = img + (size_t)b0 * HW;

    // ---- img -> REGISTERS (28 scalars/lane), issued first: latency hides
    //      under the fr staging that follows. Clamped addresses always valid;
    //      OOB masked to 0 by select. Statically indexed later (rule #20). ----
    float iw0r[14], iw1r[14];
    {
        const int gx0  = x0t - 6 + n;           // in [-6, 249]
        const int gx1  = gx0 + 16;              // in [10, 265]
        const int gx0c = max(gx0, 0);
        const int gx1c = min(gx1, WW-1);
        const bool okx0 = (gx0 >= 0);
        const bool okx1 = (gx1 < WW);
        #pragma unroll
        for (int u = 0; u < 14; ++u) {
            const int gy  = y0 - 6 + 2*w + u;
            const int gyc = min(max(gy, 0), HH-1);
            const bool oky = (gy == gyc);
            const float v0 = imb[(size_t)gyc * WW + gx0c];
            const float v1 = imb[(size_t)gyc * WW + gx1c];
            iw0r[u] = (oky && okx0) ? v0 : 0.f;
            iw1r[u] = (oky && okx1) ? v1 : 0.f;
        }
    }

    // ---- stage fr tile: f32 global -> f16 LDS (padded px stride) ----
    // granule q (ch 4q..4q+3) -> f16 offset 8*(q&3)+4*(q>>2): the 16B unit at
    // offset 16g holds ch {4g..4g+3, 16+4g..16+4g+3} = the x32 k-slice for group g.
    for (int i = tid; i < NROWS * 8 * 8; i += NTHREADS) {
        const int px4 = i & 7;         // 4-px group (NPX/4 = 8)
        const int q   = (i >> 3) & 7;  // channel granule
        const int row = i >> 6;
        const int gy  = y0 - 6 + row;
        const int gx  = x0t - 6 + px4 * 4;
        const int gyc = min(max(gy, 0), HH-1);
        const bool oky = (gy == gyc);
        const float* src = frb + ((size_t)(4*q) * HH + gyc) * WW;
        float t[4][4];
        if (oky && gx >= 0 && gx + 3 < WW) {
            #pragma unroll
            for (int jc = 0; jc < 4; ++jc) {
                float4 v = *(const float4*)(src + (size_t)jc * HW + gx);
                t[jc][0]=v.x; t[jc][1]=v.y; t[jc][2]=v.z; t[jc][3]=v.w;
            }
        } else {
            #pragma unroll
            for (int jc = 0; jc < 4; ++jc)
                #pragma unroll
                for (int e = 0; e < 4; ++e) {
                    int x = gx + e;
                    t[jc][e] = (oky && x >= 0 && x < WW) ? src[(size_t)jc * HW + x] : 0.f;
                }
        }
        const int qo = 8*(q & 3) + 4*(q >> 2);
        #pragma unroll
        for (int jp = 0; jp < 4; ++jp) {
            const int px = px4 * 4 + jp;
            v4h pk;
            pk[0] = (half_t)t[0][jp]; pk[1] = (half_t)t[1][jp];
            pk[2] = (half_t)t[2][jp]; pk[3] = (half_t)t[3][jp];
            *(v4h*)&frl[(row * NPX + px) * PXS + qo] = pk;
        }
    }

    // ---- A fragments: 2 query rows, ch {4g+j, 16+4g+j} pre-scaled by log2e ----
    const int y = y0 + 2*w;
    v8h a0, a1;
    {
        const float* fa = ftb + (size_t)y * WW + (x0t + n);
        #pragma unroll
        for (int j = 0; j < 4; ++j) {
            a0[j]   = (half_t)(fa[(size_t)(4*g + j)      * HW] * L2E);
            a0[4+j] = (half_t)(fa[(size_t)(16 + 4*g + j) * HW] * L2E);
            a1[j]   = (half_t)(fa[WW + (size_t)(4*g + j)      * HW] * L2E);
            a1[4+j] = (half_t)(fa[WW + (size_t)(16 + 4*g + j) * HW] * L2E);
        }
    }

    // ---- per-lane displacement-band biases (log2 domain; exp2(-1e4)==0) ----
    v4f bias0, bias1;
    #pragma unroll
    for (int r = 0; r < 4; ++r) {
        const int m  = 4*g + r;
        const int d0 = n - m;            // key-tile 0
        const int d1 = 16 + n - m;       // key-tile +16
        bias0[r] = (d0 >= 0 && d0 <= 12) ? 0.f : -1e4f;
        bias1[r] = (d1 >= 0 && d1 <= 12) ? 0.f : -1e4f;
    }
    const int dm = n - 4*g;              // select: cond_r = (dm >= r)

    __syncthreads();

    v4f lp0 = {0,0,0,0}, ap0 = {0,0,0,0};
    v4f lp1 = {0,0,0,0}, ap1 = {0,0,0,0};

    auto STEP = [&](const v8h& a, v4f& lp, v4f& ap,
                    const v8h& B0, const v8h& B1, float iw0, float iw1) {
        v4f c0 = __builtin_amdgcn_mfma_f32_16x16x32_f16(a, B0, bias0, 0, 0, 0);
        v4f c1 = __builtin_amdgcn_mfma_f32_16x16x32_f16(a, B1, bias1, 0, 0, 0);
        #pragma unroll
        for (int r = 0; r < 4; ++r) {
            const bool cond = (dm >= r);
            float cs  = cond ? c0[r] : c1[r];
            float iws = cond ? iw0   : iw1;
            float e = __builtin_amdgcn_exp2f(cs);
            lp[r] += e;
            ap[r] += e * iws;
        }
    };

    // ---- main loop, FULLY UNROLLED (static img indexing; ds_read base+imm):
    //      row u = LDS row 2w+u serves job0 at dy=u (u<=12), job1 at dy=u-1 (u>=1) ----
    const half_t* prd = &frl[(2*w * NPX + n) * PXS + 8*g];
    #pragma unroll
    for (int u = 0; u < 14; ++u) {
        v8h B0 = *(const v8h*)(prd + u*RSTEP);
        v8h B1 = *(const v8h*)(prd + u*RSTEP + 16*PXS);
        if (u <= 12) STEP(a0, lp0, ap0, B0, B1, iw0r[u], iw1r[u]);
        if (u >= 1)  STEP(a1, lp1, ap1, B0, B1, iw0r[u], iw1r[u]);
    }

    // ---- reduce over the 16 key-px lanes; write 2 rows × 16 px per wave ----
    #pragma unroll
    for (int r = 0; r < 4; ++r) {
        float l0 = lp0[r], v0 = ap0[r], l1 = lp1[r], v1 = ap1[r];
        l0 += __shfl_xor(l0, 1);  v0 += __shfl_xor(v0, 1);
        l1 += __shfl_xor(l1, 1);  v1 += __shfl_xor(v1, 1);
        l0 += __shfl_xor(l0, 2);  v0 += __shfl_xor(v0, 2);
        l1 += __shfl_xor(l1, 2);  v1 += __shfl_xor(v1, 2);
        l0 += __shfl_xor(l0, 4);  v0 += __shfl_xor(v0, 4);
        l1 += __shfl_xor(l1, 4);  v1 += __shfl_xor(v1, 4);
        l0 += __shfl_xor(l0, 8);  v0 += __shfl_xor(v0, 8);
        l1 += __shfl_xor(l1, 8);  v1 += __shfl_xor(v1, 8);
        lp0[r] = l0; ap0[r] = v0; lp1[r] = l1; ap1[r] = v1;
    }
    if (n < 4) {
        const float l0 = n==0 ? lp0[0] : n==1 ? lp0[1] : n==2 ? lp0[2] : lp0[3];
        const float v0 = n==0 ? ap0[0] : n==1 ? ap0[1] : n==2 ? ap0[2] : ap0[3];
        const float l1 = n==0 ? lp1[0] : n==1 ? lp1[1] : n==2 ? lp1[2] : lp1[3];
        const float v1 = n==0 ? ap1[0] : n==1 ? ap1[1] : n==2 ? ap1[2] : ap1[3];
        float* orow = out + (size_t)b0 * HW + (size_t)y * WW + x0t + 4*g + n;
        orow[0]  = v0 / l0;
        orow[WW] = v1 / l1;
    }
}

extern "C" void kernel_launch(void* const* d_in, const int* in_sizes, int n_in,
                              void* d_out, int out_size, void* d_ws, size_t ws_size,
                              hipStream_t stream)
{
    const float* ft  = (const float*)d_in[0];  // feats_t  (2,32,256,256) f32
    const float* fr  = (const float*)d_in[1];  // feats_r  (2,32,256,256) f32
    const float* img = (const float*)d_in[2];  // img_r    (2,1,256,256)  f32
    float* out = (float*)d_out;                // (2,1,256,256) f32
    (void)in_sizes; (void)n_in; (void)out_size; (void)d_ws; (void)ws_size;
    corr_recon<<<256, NTHREADS, 0, stream>>>(ft, fr, img, out);
}